// Round 1
// baseline (1450.053 us; speedup 1.0000x reference)
//
#include <hip/hip_runtime.h>

// QuantumFeedForward: out = cos^2(relu(x@W1^T + b1)) @ W2^T + b2
// N=65536 tokens, EMBED=2048, FFN=8. All fp32.
//
// v2 strategy: the previous kernel was latency/barrier-bound (VALUBusy 10%,
// HBM 27%, 128 barriers/block). This version has NO LDS and NO barriers:
//   lane <-> (token = tid>>3, e-slice = (tid&7)*4)
//   - x / out: each 8-lane group touches 128B contiguous per instruction
//     -> perfectly coalesced HBM streams.
//   - W1 / W2: address depends only on (tid&7) -> one 128B line per
//     instruction, broadcast across token groups; each wave streams the
//     64KB weight arrays through L1/L2 (negligible vs HBM time).
//   - h reduction: one 3-step __shfl_xor butterfly over the 8-lane group,
//     executed once per kernel. After it, every lane holds q[0..7] for its
//     token, so phase 2 needs no data exchange at all.

static constexpr int EMBED = 2048;
static constexpr int FFN   = 8;
static constexpr int TPB   = 32;   // tokens per block (256 threads, 8 lanes/token)

__global__ __launch_bounds__(256, 6)
void qffn_kernel(const float* __restrict__ x, const float* __restrict__ W1,
                 const float* __restrict__ b1, const float* __restrict__ W2,
                 const float* __restrict__ b2, float* __restrict__ out)
{
    const int tid = threadIdx.x;
    const int sub = tid & 7;                      // e-slice within token group
    const int t   = blockIdx.x * TPB + (tid >> 3);
    const long rowbase = (long)t * EMBED;

    const float* xp  = x + rowbase + sub * 4;
    const float* w1p = W1 + sub * 4;

    // ---------------- Phase 1: h[f] = x[t] . W1[f] (partial per lane) ----
    float4 h[FFN];
    #pragma unroll
    for (int f = 0; f < FFN; ++f) h[f] = make_float4(0.f, 0.f, 0.f, 0.f);

    #pragma unroll 2
    for (int c = 0; c < EMBED / 32; ++c) {
        const float4 xv = *(const float4*)(xp + c * 32);
        #pragma unroll
        for (int f = 0; f < FFN; ++f) {
            const float4 wv = *(const float4*)(w1p + f * EMBED + c * 32);
            h[f].x = fmaf(xv.x, wv.x, h[f].x);
            h[f].y = fmaf(xv.y, wv.y, h[f].y);
            h[f].z = fmaf(xv.z, wv.z, h[f].z);
            h[f].w = fmaf(xv.w, wv.w, h[f].w);
        }
    }

    // Butterfly-reduce the 8-lane group; all lanes end with full h[f],
    // then q[f] = cos^2(relu(h[f] + b1[f])).
    float q[FFN];
    #pragma unroll
    for (int f = 0; f < FFN; ++f) {
        float s = (h[f].x + h[f].y) + (h[f].z + h[f].w);
        s += __shfl_xor(s, 1);
        s += __shfl_xor(s, 2);
        s += __shfl_xor(s, 4);
        s = fmaxf(s + b1[f], 0.f);
        const float cv = __cosf(s);
        q[f] = cv * cv;
    }

    // ---------------- Phase 2: out[t][e] = q . W2[e][:] + b2[e] ----------
    #pragma unroll 2
    for (int c = 0; c < EMBED / 32; ++c) {
        const int e = c * 32 + sub * 4;
        const float4 bv = *(const float4*)(b2 + e);
        const float bvs[4] = {bv.x, bv.y, bv.z, bv.w};
        float o[4];
        #pragma unroll
        for (int j = 0; j < 4; ++j) {
            const float4 wlo = *(const float4*)(W2 + (e + j) * FFN);
            const float4 whi = *(const float4*)(W2 + (e + j) * FFN + 4);
            float s = bvs[j];
            s = fmaf(q[0], wlo.x, s);
            s = fmaf(q[1], wlo.y, s);
            s = fmaf(q[2], wlo.z, s);
            s = fmaf(q[3], wlo.w, s);
            s = fmaf(q[4], whi.x, s);
            s = fmaf(q[5], whi.y, s);
            s = fmaf(q[6], whi.z, s);
            s = fmaf(q[7], whi.w, s);
            o[j] = s;
        }
        *(float4*)(out + rowbase + e) = make_float4(o[0], o[1], o[2], o[3]);
    }
}

extern "C" void kernel_launch(void* const* d_in, const int* in_sizes, int n_in,
                              void* d_out, int out_size, void* d_ws, size_t ws_size,
                              hipStream_t stream) {
    const float* x  = (const float*)d_in[0];
    const float* W1 = (const float*)d_in[1];
    const float* b1 = (const float*)d_in[2];
    const float* W2 = (const float*)d_in[3];
    const float* b2 = (const float*)d_in[4];
    float* out = (float*)d_out;

    const int ntok = in_sizes[0] / EMBED;      // 65536
    qffn_kernel<<<dim3(ntok / TPB), dim3(256), 0, stream>>>(x, W1, b1, W2, b2, out);
}